// Round 1
// baseline (103.687 us; speedup 1.0000x reference)
//
#include <hip/hip_runtime.h>
#include <math.h>

#define EPS 1e-8f

typedef short bf16x8 __attribute__((ext_vector_type(8)));
typedef short bf16x4 __attribute__((ext_vector_type(4)));
typedef float f32x4  __attribute__((ext_vector_type(4)));

// fp32 -> bf16 bits, round-to-nearest-even
__device__ __forceinline__ short f2bf(float f) {
    union { float fv; unsigned u; } v; v.fv = f;
    unsigned r = v.u + 0x7fffu + ((v.u >> 16) & 1u);
    return (short)(r >> 16);
}
__device__ __forceinline__ float bf2f(short s) {
    union { unsigned u; float f; } v;
    v.u = ((unsigned)(unsigned short)s) << 16;
    return v.f;
}
__device__ __forceinline__ bf16x8 pack8(float4 a, float4 b) {
    bf16x8 p;
    p[0] = f2bf(a.x); p[1] = f2bf(a.y); p[2] = f2bf(a.z); p[3] = f2bf(a.w);
    p[4] = f2bf(b.x); p[5] = f2bf(b.y); p[6] = f2bf(b.z); p[7] = f2bf(b.w);
    return p;
}

// ---------------------------------------------------------------------------
// K1: proj + normalize + fused quaternion-pair expand.  BARRIER-FREE.
// Per-wave 16x32 output tile; MFMA fragments loaded directly from global
// (fp32 -> bf16 in registers).  1024 waves = 256 blocks x 4 waves.
// C/D layout: col = lane&15, row = (lane>>4)*4 + reg.
// ---------------------------------------------------------------------------
__global__ __launch_bounds__(256) void proj_expand_kernel(
    const float* __restrict__ vis, const float* __restrict__ txt,
    const float* __restrict__ Wv, const float* __restrict__ bv,
    const float* __restrict__ Wt, const float* __restrict__ bt,
    short* __restrict__ expq)
{
    const int t = threadIdx.x, lane = t & 63, wave = t >> 6;
    const int w  = blockIdx.x * 4 + wave;   // 0..1023
    const int rt = w >> 3;                  // 0..127  (16-row tiles over 2048 rows)
    const int ct = w & 7;                   // 0..7    (32-col tiles over 256 cols)
    const int which = rt >> 6;              // 0 = vis, 1 = txt
    const int r0 = (rt & 63) * 16;          // row base within 1024-row matrix
    const int c0 = ct * 32;
    const float* X    = which ? txt : vis;
    const float* W    = which ? Wt : Wv;
    const float* bias = which ? bt : bv;
    short* Eo = expq + which * 1024 * 1024;

    const int mrow = lane & 15, quad = lane >> 4;

    const float* Arow  = X + (r0 + mrow) * 256 + 8 * quad;
    const float* Brow0 = W + (c0 + mrow) * 256 + 8 * quad;
    const float* Brow1 = W + (c0 + 16 + mrow) * 256 + 8 * quad;

    f32x4 acc[2] = {};
    #pragma unroll 4
    for (int k0 = 0; k0 < 256; k0 += 32) {
        float4 a0 = *(const float4*)(Arow + k0);
        float4 a1 = *(const float4*)(Arow + k0 + 4);
        float4 p0 = *(const float4*)(Brow0 + k0);
        float4 p1 = *(const float4*)(Brow0 + k0 + 4);
        float4 q0 = *(const float4*)(Brow1 + k0);
        float4 q1 = *(const float4*)(Brow1 + k0 + 4);
        bf16x8 af = pack8(a0, a1);
        bf16x8 b0 = pack8(p0, p1);
        bf16x8 b1 = pack8(q0, q1);
        acc[0] = __builtin_amdgcn_mfma_f32_16x16x32_bf16(af, b0, acc[0], 0, 0, 0);
        acc[1] = __builtin_amdgcn_mfma_f32_16x16x32_bf16(af, b1, acc[1], 0, 0, 0);
    }

    const int qbase = lane & ~3;            // 4 lanes holding this quaternion
    #pragma unroll
    for (int j = 0; j < 2; ++j) {
        const int col  = c0 + 16 * j + mrow;
        const float bb = bias[col];
        const int head = col >> 2;
        #pragma unroll
        for (int reg = 0; reg < 4; ++reg) {
            const int row = r0 + quad * 4 + reg;
            float v = acc[j][reg] + bb;
            float s = v * v;
            s += __shfl_xor(s, 1, 64);
            s += __shfl_xor(s, 2, 64);
            float q = v * (1.f / (sqrtf(s) + EPS));
            float q0 = __shfl(q, qbase + 0, 64);
            float q1 = __shfl(q, qbase + 1, 64);
            float q2 = __shfl(q, qbase + 2, 64);
            float q3 = __shfl(q, qbase + 3, 64);
            bf16x4 p;
            p[0] = f2bf(q * q0); p[1] = f2bf(q * q1);
            p[2] = f2bf(q * q2); p[3] = f2bf(q * q3);
            *(bf16x4*)(Eo + row * 1024 + head * 16 + (col & 3) * 4) = p;
        }
    }
}

// ---------------------------------------------------------------------------
// K2: E[n][m] = exp(dot(expv_n, expt_m)/1024), bf16; also E^T and partial row
// sums rs[row][16].  BARRIER-FREE: fragments loaded directly from global
// (expq is bf16 row-major = exact fragment layout).  Per-wave 16(n) x 32(m),
// K=1024.  1024 waves = 256 blocks.
// ---------------------------------------------------------------------------
__global__ __launch_bounds__(256) void logits_kernel(
    const short* __restrict__ expq, short* __restrict__ E,
    short* __restrict__ ET, float* __restrict__ rs)
{
    const int t = threadIdx.x, lane = t & 63, wave = t >> 6;
    const int w  = blockIdx.x * 4 + wave;   // 0..1023
    const int b  = w >> 9;
    const int nt = (w >> 4) & 31;           // 0..31
    const int mt = w & 15;                  // 0..15
    const int r0 = nt * 16, c0 = mt * 32;
    const int mrow = lane & 15, quad = lane >> 4;

    const short* Ar  = expq + (b * 512 + r0 + mrow) * 1024 + 8 * quad;
    const short* Br0 = expq + (1024 + b * 512 + c0 + mrow) * 1024 + 8 * quad;
    const short* Br1 = Br0 + 16 * 1024;

    f32x4 acc[2] = {};
    #pragma unroll 4
    for (int k0 = 0; k0 < 1024; k0 += 32) {
        bf16x8 a  = *(const bf16x8*)(Ar  + k0);
        bf16x8 b0 = *(const bf16x8*)(Br0 + k0);
        bf16x8 b1 = *(const bf16x8*)(Br1 + k0);
        acc[0] = __builtin_amdgcn_mfma_f32_16x16x32_bf16(a, b0, acc[0], 0, 0, 0);
        acc[1] = __builtin_amdgcn_mfma_f32_16x16x32_bf16(a, b1, acc[1], 0, 0, 0);
    }

    float e[2][4];
    #pragma unroll
    for (int j = 0; j < 2; ++j)
        #pragma unroll
        for (int reg = 0; reg < 4; ++reg)
            e[j][reg] = __expf(acc[j][reg] * (1.f / 1024.f));

    #pragma unroll
    for (int j = 0; j < 2; ++j) {
        const int col = c0 + 16 * j + mrow;
        bf16x4 pe;
        #pragma unroll
        for (int reg = 0; reg < 4; ++reg) {
            pe[reg] = f2bf(e[j][reg]);
            const int row = r0 + quad * 4 + reg;
            E[(b * 512 + row) * 512 + col] = pe[reg];
        }
        // transposed store: 4 consecutive rows per lane -> one bf16x4
        *(bf16x4*)(ET + (b * 512 + col) * 512 + r0 + quad * 4) = pe;
    }
    // partial sums over this wave's 32 cols
    #pragma unroll
    for (int reg = 0; reg < 4; ++reg) {
        float p = e[0][reg] + e[1][reg];
        p += __shfl_xor(p, 1, 64);
        p += __shfl_xor(p, 2, 64);
        p += __shfl_xor(p, 4, 64);
        p += __shfl_xor(p, 8, 64);
        if (mrow == 0) {
            const int row = r0 + quad * 4 + reg;
            rs[(b * 512 + row) * 16 + (c0 >> 5)] = p;
        }
    }
}

// ---------------------------------------------------------------------------
// K2.5: finish softmax denominators + emit bf16 transposed operands for K3.
//   txtT [b][d][m]  = bf16(txt[b][m][d])
//   visST[b][d][n]  = bf16(vis[b][n][d] * rinv[n])   (softmax norm folded in)
//   rinv [b*512+n]  = 1/rowsum  (for K3 which=0 epilogue)
// grid 128: mat = bx>>6 (0 txt, 1 vis), b = (bx>>5)&1, m0 = (bx&31)*16.
// Thread t = column d (0..255); reads 16 rows coalesced, writes 32B per lane.
// ---------------------------------------------------------------------------
__global__ __launch_bounds__(256) void transpose_scale_kernel(
    const float* __restrict__ vis, const float* __restrict__ txt,
    const float* __restrict__ rs,
    short* __restrict__ txtT, short* __restrict__ visST,
    float* __restrict__ rinv)
{
    const int bx = blockIdx.x;
    const int mat = bx >> 6;                // 0 = txt, 1 = vis
    const int b   = (bx >> 5) & 1;
    const int m0  = (bx & 31) * 16;
    const int t   = threadIdx.x;            // = d

    __shared__ float rsc[16];
    if (mat == 1) {
        if (t < 16) {
            const float* p = rs + (b * 512 + m0 + t) * 16;
            float s = 0.f;
            #pragma unroll
            for (int i = 0; i < 16; ++i) s += p[i];
            const float ri = 1.f / s;
            rsc[t] = ri;
            rinv[b * 512 + m0 + t] = ri;
        }
        __syncthreads();
    }

    const float* src = (mat ? vis : txt) + (b * 512 + m0) * 256 + t;
    short* dst = (mat ? visST : txtT) + (b * 256 + t) * 512 + m0;

    bf16x8 v0, v1;
    #pragma unroll
    for (int i = 0; i < 8; ++i) {
        float a = src[i * 256];
        float c = src[(i + 8) * 256];
        if (mat) { a *= rsc[i]; c *= rsc[i + 8]; }
        v0[i] = f2bf(a);
        v1[i] = f2bf(c);
    }
    *(bf16x8*)(dst)     = v0;
    *(bf16x8*)(dst + 8) = v1;
}

// ---------------------------------------------------------------------------
// K3: outputs.  BARRIER-FREE, LDS-free: all operands bf16 row-major in
// fragment layout.
//   which=0: out_v[n][d] = vis + h*rinv[n] * sum_m E[n][m]*txtT[d][m]
//   which=1: out_t[m][d] = txt + h * sum_n ET[m][n]*visST[d][n]
// Per-wave 16 x 32(d), K=512.  1024 waves = 256 blocks.
// ---------------------------------------------------------------------------
__global__ __launch_bounds__(256) void out_kernel(
    const float* __restrict__ vis, const float* __restrict__ txt,
    const short* __restrict__ E, const short* __restrict__ ET,
    const short* __restrict__ txtT, const short* __restrict__ visST,
    const float* __restrict__ rinv, const float* __restrict__ hptr,
    float* __restrict__ outv, float* __restrict__ outt)
{
    const int t = threadIdx.x, lane = t & 63, wave = t >> 6;
    const int w     = blockIdx.x * 4 + wave;  // 0..1023
    const int which = w >> 9;
    const int b     = (w >> 8) & 1;
    const int nt    = (w >> 3) & 31;          // 0..31 row tile
    const int dt    = w & 7;                  // 0..7  d tile
    const int r0 = nt * 16, c0 = dt * 32;
    const int mrow = lane & 15, quad = lane >> 4;
    const float hv = hptr[0];

    const short* Ar  = (which ? ET : E) + (b * 512 + r0 + mrow) * 512 + 8 * quad;
    const short* Br0 = (which ? visST : txtT) + (b * 256 + c0 + mrow) * 512 + 8 * quad;
    const short* Br1 = Br0 + 16 * 512;
    const float* base = (which ? txt : vis) + (b * 512 + r0) * 256;
    float*       out  = (which ? outt : outv) + (b * 512 + r0) * 256;

    f32x4 acc[2] = {};
    #pragma unroll 4
    for (int k0 = 0; k0 < 512; k0 += 32) {
        bf16x8 a  = *(const bf16x8*)(Ar  + k0);
        bf16x8 b0 = *(const bf16x8*)(Br0 + k0);
        bf16x8 b1 = *(const bf16x8*)(Br1 + k0);
        acc[0] = __builtin_amdgcn_mfma_f32_16x16x32_bf16(a, b0, acc[0], 0, 0, 0);
        acc[1] = __builtin_amdgcn_mfma_f32_16x16x32_bf16(a, b1, acc[1], 0, 0, 0);
    }

    #pragma unroll
    for (int reg = 0; reg < 4; ++reg) {
        const int row = quad * 4 + reg;       // local row
        const float scale = which ? hv : hv * rinv[b * 512 + r0 + row];
        #pragma unroll
        for (int j = 0; j < 2; ++j) {
            const int col = c0 + 16 * j + mrow;
            out[row * 256 + col] = fmaf(scale, acc[j][reg], base[row * 256 + col]);
        }
    }
}

// ---------------------------------------------------------------------------
extern "C" void kernel_launch(void* const* d_in, const int* in_sizes, int n_in,
                              void* d_out, int out_size, void* d_ws, size_t ws_size,
                              hipStream_t stream)
{
    const float* vis = (const float*)d_in[0];
    const float* txt = (const float*)d_in[1];
    const float* Wv  = (const float*)d_in[2];
    const float* bv  = (const float*)d_in[3];
    const float* Wt  = (const float*)d_in[4];
    const float* bt  = (const float*)d_in[5];
    const float* h   = (const float*)d_in[6];

    float* outv = (float*)d_out;                  // 2*512*256
    float* outt = (float*)d_out + 2 * 512 * 256;

    short* expq  = (short*)d_ws;                  // 2048 x 1024 bf16 (4 MB)
    short* E     = expq + 2048 * 1024;            // 1024 x 512 bf16 (1 MB)
    short* ET    = E + 1024 * 512;                // 1024 x 512 bf16 (1 MB)
    float* rs    = (float*)(ET + 1024 * 512);     // 1024 x 16 fp32 (64 KB)
    float* rinv  = rs + 1024 * 16;                // 1024 fp32 (4 KB)
    short* txtT  = (short*)(rinv + 1024);         // 2 x 256 x 512 bf16 (0.5 MB)
    short* visST = txtT + 2 * 256 * 512;          // 2 x 256 x 512 bf16 (0.5 MB)

    proj_expand_kernel<<<dim3(256), 256, 0, stream>>>(vis, txt, Wv, bv, Wt, bt, expq);
    logits_kernel<<<dim3(256), 256, 0, stream>>>(expq, E, ET, rs);
    transpose_scale_kernel<<<dim3(128), 256, 0, stream>>>(vis, txt, rs, txtT, visST, rinv);
    out_kernel<<<dim3(256), 256, 0, stream>>>(vis, txt, E, ET, txtT, visST, rinv, h, outv, outt);
}